// Round 3
// baseline (215.025 us; speedup 1.0000x reference)
//
#include <hip/hip_runtime.h>
#include <math.h>

typedef __bf16 bf16x8 __attribute__((ext_vector_type(8)));
typedef float f32x4 __attribute__((ext_vector_type(4)));

#define GPTR(p) ((const __attribute__((address_space(1))) void*)(p))
#define LPTR(p) ((__attribute__((address_space(3))) void*)(p))

// softmax scale folded into Q: 1/sqrt(64) * log2(e)
#define QSCALE 0.18033688011112042f

__device__ __forceinline__ unsigned short f2bf(float f) {
  unsigned int u = __float_as_uint(f);
  u += 0x7FFFu + ((u >> 16) & 1u);   // RNE; inputs are finite
  return (unsigned short)(u >> 16);
}

// pack two positive floats to bf16x2 (round-half-up) in 3 VALU ops
__device__ __forceinline__ unsigned int pack_bf2(float lo, float hi) {
  return __builtin_amdgcn_perm(__float_as_uint(hi) + 0x8000u,
                               __float_as_uint(lo) + 0x8000u, 0x07060302u);
}

__device__ __forceinline__ float fast_exp2(float x) {
#if __has_builtin(__builtin_amdgcn_exp2f)
  return __builtin_amdgcn_exp2f(x);
#else
  return exp2f(x);
#endif
}

__device__ __forceinline__ f32x4 zero4() {
  f32x4 z; z[0] = 0.f; z[1] = 0.f; z[2] = 0.f; z[3] = 0.f; return z;
}

// gfx950 cross-lane row swaps (rows = 16-lane groups).
// swap32: a' = [a.r0, a.r1, b.r0, b.r1], b' = [a.r2, a.r3, b.r2, b.r3]
__device__ __forceinline__ void permlane_swap32(unsigned int& a, unsigned int& b) {
  asm("v_permlane32_swap_b32 %0, %1" : "+v"(a), "+v"(b));
}
// swap16: a' = [a.r0, b.r0, a.r2, b.r2], b' = [a.r1, b.r1, a.r3, b.r3]
__device__ __forceinline__ void permlane_swap16(unsigned int& a, unsigned int& b) {
  asm("v_permlane16_swap_b32 %0, %1" : "+v"(a), "+v"(b));
}

// ---------- fp32 -> bf16 elementwise ----------
__global__ void conv_x_bf16(const float* __restrict__ in, unsigned short* __restrict__ out) {
  int i = (blockIdx.x * 256 + threadIdx.x) * 4;
  float4 v = *(const float4*)(in + i);
  ushort4 o;
  o.x = f2bf(v.x); o.y = f2bf(v.y); o.z = f2bf(v.z); o.w = f2bf(v.w);
  *(ushort4*)(out + i) = o;
}

// ---------- out[n][k] = bf16(in[k][n]); in is [K][N] fp32 ----------
__global__ void transpose_conv(const float* __restrict__ in, unsigned short* __restrict__ out,
                               int K, int N) {
  __shared__ float tile[64][65];
  int k0 = blockIdx.y * 64, n0 = blockIdx.x * 64;
  int t = threadIdx.x;
#pragma unroll
  for (int p = 0; p < 16; ++p) {
    int l = p * 256 + t; int r = l >> 6, c = l & 63;
    tile[r][c] = in[(size_t)(k0 + r) * N + n0 + c];
  }
  __syncthreads();
#pragma unroll
  for (int p = 0; p < 16; ++p) {
    int l = p * 256 + t; int r = l >> 6, c = l & 63;
    out[(size_t)(n0 + r) * K + k0 + c] = f2bf(tile[c][r]);
  }
}

// ---------- QKV projection: C = A @ Bt^T + bias ----------
// Q -> row-major [bh][2048][64], pre-scaled by QSCALE.
// K -> tiled+swizzled [bh][tile32][64 r][8 chunks], chunk c stored at c^(r&7).
// V -> tiled+swizzled [bh][tile32][64 d][8 chunks over t], chunk c at c^(d&7).
__global__ __launch_bounds__(256) void gemm_qkv(
    const unsigned short* __restrict__ A, const unsigned short* __restrict__ Bt,
    const float* __restrict__ bias,
    unsigned short* __restrict__ Qd, unsigned short* __restrict__ Kd,
    unsigned short* __restrict__ Vtd) {
  __shared__ unsigned short As[128 * 32];
  __shared__ unsigned short Bs[128 * 32];
  const int tid = threadIdx.x, wave = tid >> 6, lane = tid & 63;
  const int quad = lane >> 4, l16 = lane & 15;
  const int wm = (wave >> 1) * 64, wn = (wave & 1) * 64;
  const int m0 = blockIdx.y * 128, n0 = blockIdx.x * 128;
  f32x4 acc[4][4];
#pragma unroll
  for (int i = 0; i < 4; ++i)
#pragma unroll
    for (int j = 0; j < 4; ++j) acc[i][j] = zero4();

  const int c = wave * 64 + lane;
  const int rA = c >> 2, o16 = (c & 3) * 8;

  for (int k0 = 0; k0 < 1024; k0 += 32) {
    __syncthreads();
    __builtin_amdgcn_global_load_lds(GPTR(A + (size_t)(m0 + rA) * 1024 + k0 + o16),
                                     LPTR(As + wave * 512), 16, 0, 0);
    __builtin_amdgcn_global_load_lds(GPTR(A + (size_t)(m0 + 64 + rA) * 1024 + k0 + o16),
                                     LPTR(As + 2048 + wave * 512), 16, 0, 0);
    __builtin_amdgcn_global_load_lds(GPTR(Bt + (size_t)(n0 + rA) * 1024 + k0 + o16),
                                     LPTR(Bs + wave * 512), 16, 0, 0);
    __builtin_amdgcn_global_load_lds(GPTR(Bt + (size_t)(n0 + 64 + rA) * 1024 + k0 + o16),
                                     LPTR(Bs + 2048 + wave * 512), 16, 0, 0);
    __syncthreads();
    bf16x8 af[4], bfr[4];
#pragma unroll
    for (int mt = 0; mt < 4; ++mt)
      af[mt] = *(const bf16x8*)(As + (wm + mt * 16 + l16) * 32 + quad * 8);
#pragma unroll
    for (int nt = 0; nt < 4; ++nt)
      bfr[nt] = *(const bf16x8*)(Bs + (wn + nt * 16 + l16) * 32 + quad * 8);
#pragma unroll
    for (int mt = 0; mt < 4; ++mt)
#pragma unroll
      for (int nt = 0; nt < 4; ++nt)
        acc[mt][nt] = __builtin_amdgcn_mfma_f32_16x16x32_bf16(af[mt], bfr[nt], acc[mt][nt], 0, 0, 0);
  }

  // Epilogue: C layout col=lane&15, row=quad*4+reg. n -> (h, q/k/v, d); m -> (b, t).
#pragma unroll
  for (int mt = 0; mt < 4; ++mt) {
#pragma unroll
    for (int nt = 0; nt < 4; ++nt) {
      int m = m0 + wm + mt * 16 + quad * 4;
      int n = n0 + wn + nt * 16 + l16;
      float bv = bias[n];
      int h = n / 192, rem = n - h * 192;
      int which = rem >> 6, d = rem & 63;
      int b = m >> 11, t0 = m & 2047;
      size_t head = (size_t)(b * 16 + h);
      f32x4 a = acc[mt][nt];
      if (which == 0) {                    // Q row-major, pre-scaled
        size_t base = (head * 2048 + t0) * 64 + d;
#pragma unroll
        for (int i = 0; i < 4; ++i)
          Qd[base + (size_t)i * 64] = f2bf((a[i] + bv) * QSCALE);
      } else if (which == 1) {             // K tiled+swizzled
        size_t base = head * 131072 + (size_t)(t0 >> 6) * 4096;
#pragma unroll
        for (int i = 0; i < 4; ++i) {
          int tt = t0 + i;
          Kd[base + (tt & 63) * 64 + (((d >> 3) ^ (tt & 7)) << 3) + (d & 7)] = f2bf(a[i] + bv);
        }
      } else {                             // V tiled+swizzled (rows = d, cols = t)
        size_t base = head * 131072 + (size_t)(t0 >> 6) * 4096;
        ushort4 o;
        o.x = f2bf(a[0] + bv); o.y = f2bf(a[1] + bv);
        o.z = f2bf(a[2] + bv); o.w = f2bf(a[3] + bv);
        *(ushort4*)(Vtd + base + d * 64 + (((((t0 & 63) >> 3)) ^ (d & 7)) << 3) + (t0 & 7)) = o;
      }
    }
  }
}

// ---------- Flash attention v6: 64 q/block (16 q/wave), 4 blocks/CU ----------
// grid (T/64, B*H). Same in-register P (permlane) + double-buffered K/V as v5,
// but half the q-tile per wave: occupancy 2 -> 4 waves/SIMD so the exp chain,
// LDS reads and MFMA of different waves interleave. Staging unchanged (256
// threads stage the 8 KB K/V tiles).
__global__ __launch_bounds__(256) void flash_attn(
    const unsigned short* __restrict__ Qg,   // [bh][2048][64] row-major, scaled
    const unsigned short* __restrict__ Kg,   // [bh][32][4096] swizzled tiles
    const unsigned short* __restrict__ Vg,   // [bh][32][4096] swizzled tiles
    unsigned short* __restrict__ att) {      // [4096][1024] bf16
  __shared__ unsigned short Ks[2][4096];
  __shared__ unsigned short Vs[2][4096];
  const int tid = threadIdx.x, wave = tid >> 6, lane = tid & 63;
  const int quad = lane >> 4, l16 = lane & 15;
  const int h7 = l16 & 7;
  const int bh = blockIdx.y;
  const int q0 = blockIdx.x * 64 + wave * 16;

  // Q B-frags: [kh], lane l16 = q-col, k = kh*32 + quad*8 + j
  bf16x8 bq[2];
#pragma unroll
  for (int kh = 0; kh < 2; ++kh)
    bq[kh] = *(const bf16x8*)(Qg + ((size_t)bh * 2048 + q0 + l16) * 64 + kh * 32 + quad * 8);

  f32x4 o[4];
#pragma unroll
  for (int i = 0; i < 4; ++i) o[i] = zero4();
  float l_run = 0.f;

  const unsigned short* Kt = Kg + (size_t)bh * 131072 + lane * 8;  // per-lane 16B src
  const unsigned short* Vt = Vg + (size_t)bh * 131072 + lane * 8;
  const int so0 = wave * 512, so1 = (4 + wave) * 512;

#define STAGE_KV(buf, tile)                                                              \
  do {                                                                                   \
    const unsigned short* Kb_ = Kt + (tile) * 4096;                                      \
    const unsigned short* Vb_ = Vt + (tile) * 4096;                                      \
    __builtin_amdgcn_global_load_lds(GPTR(Kb_ + so0), LPTR(&Ks[buf][so0]), 16, 0, 0);    \
    __builtin_amdgcn_global_load_lds(GPTR(Kb_ + so1), LPTR(&Ks[buf][so1]), 16, 0, 0);    \
    __builtin_amdgcn_global_load_lds(GPTR(Vb_ + so0), LPTR(&Vs[buf][so0]), 16, 0, 0);    \
    __builtin_amdgcn_global_load_lds(GPTR(Vb_ + so1), LPTR(&Vs[buf][so1]), 16, 0, 0);    \
  } while (0)

  STAGE_KV(0, 0);
  __syncthreads();                           // tile 0 staged & visible

  int cur = 0;
  for (int tile = 0; tile < 32; ++tile) {
    if (tile < 31) STAGE_KV(cur ^ 1, tile + 1);  // prefetch next tile (in flight over compute)

    // ---- S^T = K · Q^T : s[kt] covers keys kt*16+quad*4+r, q = l16
    f32x4 s[4];
#pragma unroll
    for (int kt = 0; kt < 4; ++kt) s[kt] = zero4();
#pragma unroll
    for (int kt = 0; kt < 4; ++kt) {
#pragma unroll
      for (int kh = 0; kh < 2; ++kh) {
        bf16x8 a = *(const bf16x8*)(&Ks[cur][(kt * 16 + l16) * 64 + (((kh * 4 + quad) ^ h7) << 3)]);
        s[kt] = __builtin_amdgcn_mfma_f32_16x16x32_bf16(a, bq[kh], s[kt], 0, 0, 0);
      }
    }

    // ---- softmax (no max subtraction), pack P to bf16 pairs in registers ----
    float lsum = 0.f;
    float pv[4][4];
#pragma unroll
    for (int kt = 0; kt < 4; ++kt)
#pragma unroll
      for (int r = 0; r < 4; ++r) {
        float p = fast_exp2(s[kt][r]);
        pv[kt][r] = p;
        lsum += p;
      }
    unsigned int pw[4][2];      // [kt][c]: keys kt*16 + quad*4 + 2c + {0,1}
#pragma unroll
    for (int kt = 0; kt < 4; ++kt) {
      pw[kt][0] = pack_bf2(pv[kt][0], pv[kt][1]);
      pw[kt][1] = pack_bf2(pv[kt][2], pv[kt][3]);
    }
    lsum += __shfl_xor(lsum, 16);
    lsum += __shfl_xor(lsum, 32);
    l_run += lsum;

    // ---- P redistribution in-register: build PV B-frags ----
    // pair (w[2st][c], w[2st+1][c]) --swap32--> --swap16--> words j2=c, j2=c+2
    bf16x8 pf[2];               // [st]: keys st*32 + quad*8 + j, q col = l16
#pragma unroll
    for (int st = 0; st < 2; ++st) {
      unsigned int a0 = pw[2 * st][0], b0 = pw[2 * st + 1][0];
      unsigned int a1 = pw[2 * st][1], b1 = pw[2 * st + 1][1];
      permlane_swap32(a0, b0); permlane_swap16(a0, b0);
      permlane_swap32(a1, b1); permlane_swap16(a1, b1);
      union { unsigned int u[4]; bf16x8 v; } x;
      x.u[0] = a0; x.u[1] = a1; x.u[2] = b0; x.u[3] = b1;
      pf[st] = x.v;
    }

    // ---- O^T += V^T · P^T ----
#pragma unroll
    for (int st = 0; st < 2; ++st) {
#pragma unroll
      for (int mt = 0; mt < 4; ++mt) {
        bf16x8 av = *(const bf16x8*)(&Vs[cur][(mt * 16 + l16) * 64 + (((st * 4 + quad) ^ h7) << 3)]);
        o[mt] = __builtin_amdgcn_mfma_f32_16x16x32_bf16(av, pf[st], o[mt], 0, 0, 0);
      }
    }

    __syncthreads();   // drains prefetch loads + protects buf reuse
    cur ^= 1;
  }
#undef STAGE_KV

  int b = bh >> 4, h = bh & 15;
  float inv_l = 1.f / l_run;
  unsigned short* orow = att + ((size_t)b * 2048 + q0 + l16) * 1024 + h * 64;
#pragma unroll
  for (int mt = 0; mt < 4; ++mt) {         // O^T: d = mt*16 + quad*4 + reg, q col = l16
    ushort4 ov;
    ov.x = f2bf(o[mt][0] * inv_l);
    ov.y = f2bf(o[mt][1] * inv_l);
    ov.z = f2bf(o[mt][2] * inv_l);
    ov.w = f2bf(o[mt][3] * inv_l);
    *(ushort4*)(orow + mt * 16 + quad * 4) = ov;
  }
}

// ---------- Output projection v2: 128x64 tiles, 512 blocks = 2/CU ----------
// out = att @ Wot^T + bias, fp32 out. Waves 2x2: each 64 rows x 32 cols.
__global__ __launch_bounds__(256) void gemm_out(
    const unsigned short* __restrict__ A, const unsigned short* __restrict__ Bt,
    const float* __restrict__ bias, float* __restrict__ out) {
  __shared__ unsigned short As[128 * 32];  // 8 KB
  __shared__ unsigned short Bs[64 * 32];   // 4 KB
  const int tid = threadIdx.x, wave = tid >> 6, lane = tid & 63;
  const int quad = lane >> 4, l16 = lane & 15;
  const int wm = (wave >> 1) * 64, wn = (wave & 1) * 32;
  const int m0 = blockIdx.y * 128, n0 = blockIdx.x * 64;
  f32x4 acc[4][2];
#pragma unroll
  for (int i = 0; i < 4; ++i)
#pragma unroll
    for (int j = 0; j < 2; ++j) acc[i][j] = zero4();

  const int c = wave * 64 + lane;
  const int rA = c >> 2, o16 = (c & 3) * 8;   // rows 0..63, 8-elem chunk

  for (int k0 = 0; k0 < 1024; k0 += 32) {
    __syncthreads();
    __builtin_amdgcn_global_load_lds(GPTR(A + (size_t)(m0 + rA) * 1024 + k0 + o16),
                                     LPTR(As + wave * 512), 16, 0, 0);
    __builtin_amdgcn_global_load_lds(GPTR(A + (size_t)(m0 + 64 + rA) * 1024 + k0 + o16),
                                     LPTR(As + 2048 + wave * 512), 16, 0, 0);
    __builtin_amdgcn_global_load_lds(GPTR(Bt + (size_t)(n0 + rA) * 1024 + k0 + o16),
                                     LPTR(Bs + wave * 512), 16, 0, 0);
    __syncthreads();
    bf16x8 af[4], bfr[2];
#pragma unroll
    for (int mt = 0; mt < 4; ++mt)
      af[mt] = *(const bf16x8*)(As + (wm + mt * 16 + l16) * 32 + quad * 8);
#pragma unroll
    for (int nt = 0; nt < 2; ++nt)
      bfr[nt] = *(const bf16x8*)(Bs + (wn + nt * 16 + l16) * 32 + quad * 8);
#pragma unroll
    for (int mt = 0; mt < 4; ++mt)
#pragma unroll
      for (int nt = 0; nt < 2; ++nt)
        acc[mt][nt] = __builtin_amdgcn_mfma_f32_16x16x32_bf16(af[mt], bfr[nt], acc[mt][nt], 0, 0, 0);
  }

#pragma unroll
  for (int mt = 0; mt < 4; ++mt) {
#pragma unroll
    for (int nt = 0; nt < 2; ++nt) {
      int m = m0 + wm + mt * 16 + quad * 4;
      int n = n0 + wn + nt * 16 + l16;
      float bv = bias[n];
      float* orow = out + (size_t)m * 1024 + n;
      orow[0]        = acc[mt][nt][0] + bv;
      orow[1024]     = acc[mt][nt][1] + bv;
      orow[2 * 1024] = acc[mt][nt][2] + bv;
      orow[3 * 1024] = acc[mt][nt][3] + bv;
    }
  }
}

extern "C" void kernel_launch(void* const* d_in, const int* in_sizes, int n_in,
                              void* d_out, int out_size, void* d_ws, size_t ws_size,
                              hipStream_t stream) {
  const float* x    = (const float*)d_in[0];   // [2,2048,1024]
  const float* Wqkv = (const float*)d_in[1];   // [1024,3072]
  const float* bqkv = (const float*)d_in[2];   // [3072]
  const float* Wo   = (const float*)d_in[3];   // [1024,1024]
  const float* bo   = (const float*)d_in[4];   // [1024]
  float* out = (float*)d_out;

  // workspace layout (bf16 = unsigned short)
  unsigned short* xb    = (unsigned short*)d_ws;                 // 4096*1024
  unsigned short* wqkvt = xb    + (size_t)4096 * 1024;           // 3072*1024
  unsigned short* wot   = wqkvt + (size_t)3072 * 1024;           // 1024*1024
  unsigned short* Qd    = wot   + (size_t)1024 * 1024;           // [32][2048][64] scaled
  unsigned short* Kd    = Qd    + (size_t)32 * 2048 * 64;        // [32][32][4096] swizzled
  unsigned short* Vtd   = Kd    + (size_t)32 * 2048 * 64;        // [32][32][4096] swizzled
  unsigned short* attb  = Vtd   + (size_t)32 * 2048 * 64;        // 4096*1024

  conv_x_bf16<<<4096, 256, 0, stream>>>(x, xb);
  transpose_conv<<<dim3(48, 16), 256, 0, stream>>>(Wqkv, wqkvt, 1024, 3072);
  transpose_conv<<<dim3(16, 16), 256, 0, stream>>>(Wo, wot, 1024, 1024);
  gemm_qkv<<<dim3(24, 32), 256, 0, stream>>>(xb, wqkvt, bqkv, Qd, Kd, Vtd);
  flash_attn<<<dim3(32, 32), 256, 0, stream>>>(Qd, Kd, Vtd, attb);
  gemm_out<<<dim3(16, 32), 256, 0, stream>>>(attb, wot, bo, out);
}

// Round 4
// 212.911 us; speedup vs baseline: 1.0099x; 1.0099x over previous
//
#include <hip/hip_runtime.h>
#include <math.h>

typedef __bf16 bf16x8 __attribute__((ext_vector_type(8)));
typedef float f32x4 __attribute__((ext_vector_type(4)));

#define GPTR(p) ((const __attribute__((address_space(1))) void*)(p))
#define LPTR(p) ((__attribute__((address_space(3))) void*)(p))

// softmax scale folded into Q: 1/sqrt(64) * log2(e)
#define QSCALE 0.18033688011112042f

__device__ __forceinline__ unsigned short f2bf(float f) {
  unsigned int u = __float_as_uint(f);
  u += 0x7FFFu + ((u >> 16) & 1u);   // RNE; inputs are finite
  return (unsigned short)(u >> 16);
}

// pack two positive floats to bf16x2 (round-half-up) in 3 VALU ops
__device__ __forceinline__ unsigned int pack_bf2(float lo, float hi) {
  return __builtin_amdgcn_perm(__float_as_uint(hi) + 0x8000u,
                               __float_as_uint(lo) + 0x8000u, 0x07060302u);
}

__device__ __forceinline__ float fast_exp2(float x) {
#if __has_builtin(__builtin_amdgcn_exp2f)
  return __builtin_amdgcn_exp2f(x);
#else
  return exp2f(x);
#endif
}

__device__ __forceinline__ f32x4 zero4() {
  f32x4 z; z[0] = 0.f; z[1] = 0.f; z[2] = 0.f; z[3] = 0.f; return z;
}

// gfx950 cross-lane row swaps (rows = 16-lane groups).
// swap32: a' = [a.r0, a.r1, b.r0, b.r1], b' = [a.r2, a.r3, b.r2, b.r3]
__device__ __forceinline__ void permlane_swap32(unsigned int& a, unsigned int& b) {
  asm("v_permlane32_swap_b32 %0, %1" : "+v"(a), "+v"(b));
}
// swap16: a' = [a.r0, b.r0, a.r2, b.r2], b' = [a.r1, b.r1, a.r3, b.r3]
__device__ __forceinline__ void permlane_swap16(unsigned int& a, unsigned int& b) {
  asm("v_permlane16_swap_b32 %0, %1" : "+v"(a), "+v"(b));
}

// ---------- fp32 -> bf16 elementwise ----------
__global__ void conv_x_bf16(const float* __restrict__ in, unsigned short* __restrict__ out) {
  int i = (blockIdx.x * 256 + threadIdx.x) * 4;
  float4 v = *(const float4*)(in + i);
  ushort4 o;
  o.x = f2bf(v.x); o.y = f2bf(v.y); o.z = f2bf(v.z); o.w = f2bf(v.w);
  *(ushort4*)(out + i) = o;
}

// ---------- out[n][k] = bf16(in[k][n]); in is [K][N] fp32 ----------
__global__ void transpose_conv(const float* __restrict__ in, unsigned short* __restrict__ out,
                               int K, int N) {
  __shared__ float tile[64][65];
  int k0 = blockIdx.y * 64, n0 = blockIdx.x * 64;
  int t = threadIdx.x;
#pragma unroll
  for (int p = 0; p < 16; ++p) {
    int l = p * 256 + t; int r = l >> 6, c = l & 63;
    tile[r][c] = in[(size_t)(k0 + r) * N + n0 + c];
  }
  __syncthreads();
#pragma unroll
  for (int p = 0; p < 16; ++p) {
    int l = p * 256 + t; int r = l >> 6, c = l & 63;
    out[(size_t)(n0 + r) * K + k0 + c] = f2bf(tile[c][r]);
  }
}

// ---------- QKV projection: C = A @ Bt^T + bias ----------
// Q -> row-major [bh][2048][64], pre-scaled by QSCALE.
// K -> tiled+swizzled [bh][tile32][64 r][8 chunks], chunk c stored at c^(r&7).
// V -> tiled+swizzled [bh][tile32][64 d][8 chunks over t], chunk c at c^(d&7).
__global__ __launch_bounds__(256) void gemm_qkv(
    const unsigned short* __restrict__ A, const unsigned short* __restrict__ Bt,
    const float* __restrict__ bias,
    unsigned short* __restrict__ Qd, unsigned short* __restrict__ Kd,
    unsigned short* __restrict__ Vtd) {
  __shared__ unsigned short As[128 * 32];
  __shared__ unsigned short Bs[128 * 32];
  const int tid = threadIdx.x, wave = tid >> 6, lane = tid & 63;
  const int quad = lane >> 4, l16 = lane & 15;
  const int wm = (wave >> 1) * 64, wn = (wave & 1) * 64;
  const int m0 = blockIdx.y * 128, n0 = blockIdx.x * 128;
  f32x4 acc[4][4];
#pragma unroll
  for (int i = 0; i < 4; ++i)
#pragma unroll
    for (int j = 0; j < 4; ++j) acc[i][j] = zero4();

  const int c = wave * 64 + lane;
  const int rA = c >> 2, o16 = (c & 3) * 8;

  for (int k0 = 0; k0 < 1024; k0 += 32) {
    __syncthreads();
    __builtin_amdgcn_global_load_lds(GPTR(A + (size_t)(m0 + rA) * 1024 + k0 + o16),
                                     LPTR(As + wave * 512), 16, 0, 0);
    __builtin_amdgcn_global_load_lds(GPTR(A + (size_t)(m0 + 64 + rA) * 1024 + k0 + o16),
                                     LPTR(As + 2048 + wave * 512), 16, 0, 0);
    __builtin_amdgcn_global_load_lds(GPTR(Bt + (size_t)(n0 + rA) * 1024 + k0 + o16),
                                     LPTR(Bs + wave * 512), 16, 0, 0);
    __builtin_amdgcn_global_load_lds(GPTR(Bt + (size_t)(n0 + 64 + rA) * 1024 + k0 + o16),
                                     LPTR(Bs + 2048 + wave * 512), 16, 0, 0);
    __syncthreads();
    bf16x8 af[4], bfr[4];
#pragma unroll
    for (int mt = 0; mt < 4; ++mt)
      af[mt] = *(const bf16x8*)(As + (wm + mt * 16 + l16) * 32 + quad * 8);
#pragma unroll
    for (int nt = 0; nt < 4; ++nt)
      bfr[nt] = *(const bf16x8*)(Bs + (wn + nt * 16 + l16) * 32 + quad * 8);
#pragma unroll
    for (int mt = 0; mt < 4; ++mt)
#pragma unroll
      for (int nt = 0; nt < 4; ++nt)
        acc[mt][nt] = __builtin_amdgcn_mfma_f32_16x16x32_bf16(af[mt], bfr[nt], acc[mt][nt], 0, 0, 0);
  }

  // Epilogue: C layout col=lane&15, row=quad*4+reg. n -> (h, q/k/v, d); m -> (b, t).
#pragma unroll
  for (int mt = 0; mt < 4; ++mt) {
#pragma unroll
    for (int nt = 0; nt < 4; ++nt) {
      int m = m0 + wm + mt * 16 + quad * 4;
      int n = n0 + wn + nt * 16 + l16;
      float bv = bias[n];
      int h = n / 192, rem = n - h * 192;
      int which = rem >> 6, d = rem & 63;
      int b = m >> 11, t0 = m & 2047;
      size_t head = (size_t)(b * 16 + h);
      f32x4 a = acc[mt][nt];
      if (which == 0) {                    // Q row-major, pre-scaled
        size_t base = (head * 2048 + t0) * 64 + d;
#pragma unroll
        for (int i = 0; i < 4; ++i)
          Qd[base + (size_t)i * 64] = f2bf((a[i] + bv) * QSCALE);
      } else if (which == 1) {             // K tiled+swizzled
        size_t base = head * 131072 + (size_t)(t0 >> 6) * 4096;
#pragma unroll
        for (int i = 0; i < 4; ++i) {
          int tt = t0 + i;
          Kd[base + (tt & 63) * 64 + (((d >> 3) ^ (tt & 7)) << 3) + (d & 7)] = f2bf(a[i] + bv);
        }
      } else {                             // V tiled+swizzled (rows = d, cols = t)
        size_t base = head * 131072 + (size_t)(t0 >> 6) * 4096;
        ushort4 o;
        o.x = f2bf(a[0] + bv); o.y = f2bf(a[1] + bv);
        o.z = f2bf(a[2] + bv); o.w = f2bf(a[3] + bv);
        *(ushort4*)(Vtd + base + d * 64 + (((((t0 & 63) >> 3)) ^ (d & 7)) << 3) + (t0 & 7)) = o;
      }
    }
  }
}

// ---------- Flash attention v7: cross-tile software pipeline ----------
// v5 geometry (128 q/block, 32 q/wave, 2 blocks/CU) + per-wave 2-stage pipeline:
// iteration t issues QK^T MFMAs for tile t (consumed NEXT iteration) and runs
// softmax+PV for tile t-1 (VALU independent of the in-flight MFMAs). Breaks the
// serial QK->exp->PV chain whose pipe-busy fractions summed to ~wallclock
// (42% VALU + 21% MFMA + ~27% LDS). K double-buffered; V TRIPLE-buffered
// (V(t-1) is read in iter t while V(t+1) is staged — 2 buffers would race).
// Scores double-buffered in regs (sA/sB) via 2x-unrolled loop (static indexing).
__global__ __launch_bounds__(256) void flash_attn(
    const unsigned short* __restrict__ Qg,   // [bh][2048][64] row-major, scaled
    const unsigned short* __restrict__ Kg,   // [bh][32][4096] swizzled tiles
    const unsigned short* __restrict__ Vg,   // [bh][32][4096] swizzled tiles
    unsigned short* __restrict__ att) {      // [4096][1024] bf16
  __shared__ unsigned short Ks[2][4096];
  __shared__ unsigned short Vs[3][4096];
  const int tid = threadIdx.x, wave = tid >> 6, lane = tid & 63;
  const int quad = lane >> 4, l16 = lane & 15;
  const int h7 = l16 & 7;
  const int bh = blockIdx.y;
  const int q0 = blockIdx.x * 128 + wave * 32;

  // Q B-frags: [qg][kh], lane l16 = q-col, k = kh*32 + quad*8 + j
  bf16x8 bq[2][2];
#pragma unroll
  for (int qg = 0; qg < 2; ++qg)
#pragma unroll
    for (int kh = 0; kh < 2; ++kh)
      bq[qg][kh] = *(const bf16x8*)(Qg + ((size_t)bh * 2048 + q0 + qg * 16 + l16) * 64 + kh * 32 + quad * 8);

  f32x4 o[2][4];
#pragma unroll
  for (int qg = 0; qg < 2; ++qg)
#pragma unroll
    for (int i = 0; i < 4; ++i) o[qg][i] = zero4();
  float l_run[2] = {0.f, 0.f};

  f32x4 sA[2][4], sB[2][4];                  // score double-buffer (prev/next)

  const unsigned short* Kt = Kg + (size_t)bh * 131072 + lane * 8;  // per-lane 16B src
  const unsigned short* Vt = Vg + (size_t)bh * 131072 + lane * 8;
  const int so0 = wave * 512, so1 = (4 + wave) * 512;

#define STAGE_K(buf, tile)                                                               \
  do {                                                                                   \
    const unsigned short* Kb_ = Kt + (tile) * 4096;                                      \
    __builtin_amdgcn_global_load_lds(GPTR(Kb_ + so0), LPTR(&Ks[buf][so0]), 16, 0, 0);    \
    __builtin_amdgcn_global_load_lds(GPTR(Kb_ + so1), LPTR(&Ks[buf][so1]), 16, 0, 0);    \
  } while (0)
#define STAGE_V(buf, tile)                                                               \
  do {                                                                                   \
    const unsigned short* Vb_ = Vt + (tile) * 4096;                                      \
    __builtin_amdgcn_global_load_lds(GPTR(Vb_ + so0), LPTR(&Vs[buf][so0]), 16, 0, 0);    \
    __builtin_amdgcn_global_load_lds(GPTR(Vb_ + so1), LPTR(&Vs[buf][so1]), 16, 0, 0);    \
  } while (0)

// QK^T for tile read from Ks[KR] into SN
#define QK(SN, KR)                                                                       \
  do {                                                                                   \
    _Pragma("unroll")                                                                    \
    for (int qg = 0; qg < 2; ++qg)                                                       \
      _Pragma("unroll")                                                                  \
      for (int kt = 0; kt < 4; ++kt) SN[qg][kt] = zero4();                               \
    _Pragma("unroll")                                                                    \
    for (int kt = 0; kt < 4; ++kt) {                                                     \
      _Pragma("unroll")                                                                  \
      for (int kh = 0; kh < 2; ++kh) {                                                   \
        bf16x8 a_ = *(const bf16x8*)(&Ks[KR][(kt * 16 + l16) * 64 + (((kh * 4 + quad) ^ h7) << 3)]); \
        SN[0][kt] = __builtin_amdgcn_mfma_f32_16x16x32_bf16(a_, bq[0][kh], SN[0][kt], 0, 0, 0); \
        SN[1][kt] = __builtin_amdgcn_mfma_f32_16x16x32_bf16(a_, bq[1][kh], SN[1][kt], 0, 0, 0); \
      }                                                                                  \
    }                                                                                    \
  } while (0)

// softmax on SP (scores of tile whose V lives in Vs[VR]) + PV accumulate
#define SOFTMAX_PV(SP, VR)                                                               \
  do {                                                                                   \
    unsigned int pw_[2][4][2];                                                           \
    _Pragma("unroll")                                                                    \
    for (int qg = 0; qg < 2; ++qg) {                                                     \
      float lsum_ = 0.f;                                                                 \
      float pv_[4][4];                                                                   \
      _Pragma("unroll")                                                                  \
      for (int kt = 0; kt < 4; ++kt)                                                     \
        _Pragma("unroll")                                                                \
        for (int r = 0; r < 4; ++r) {                                                    \
          float p_ = fast_exp2(SP[qg][kt][r]);                                           \
          pv_[kt][r] = p_;                                                               \
          lsum_ += p_;                                                                   \
        }                                                                                \
      _Pragma("unroll")                                                                  \
      for (int kt = 0; kt < 4; ++kt) {                                                   \
        pw_[qg][kt][0] = pack_bf2(pv_[kt][0], pv_[kt][1]);                               \
        pw_[qg][kt][1] = pack_bf2(pv_[kt][2], pv_[kt][3]);                               \
      }                                                                                  \
      lsum_ += __shfl_xor(lsum_, 16);                                                    \
      lsum_ += __shfl_xor(lsum_, 32);                                                    \
      l_run[qg] += lsum_;                                                                \
    }                                                                                    \
    bf16x8 pf_[2][2];                                                                    \
    _Pragma("unroll")                                                                    \
    for (int qg = 0; qg < 2; ++qg) {                                                     \
      _Pragma("unroll")                                                                  \
      for (int st = 0; st < 2; ++st) {                                                   \
        unsigned int a0_ = pw_[qg][2 * st][0], b0_ = pw_[qg][2 * st + 1][0];             \
        unsigned int a1_ = pw_[qg][2 * st][1], b1_ = pw_[qg][2 * st + 1][1];             \
        permlane_swap32(a0_, b0_); permlane_swap16(a0_, b0_);                            \
        permlane_swap32(a1_, b1_); permlane_swap16(a1_, b1_);                            \
        union { unsigned int u[4]; bf16x8 v; } x_;                                       \
        x_.u[0] = a0_; x_.u[1] = a1_; x_.u[2] = b0_; x_.u[3] = b1_;                      \
        pf_[qg][st] = x_.v;                                                              \
      }                                                                                  \
    }                                                                                    \
    _Pragma("unroll")                                                                    \
    for (int st = 0; st < 2; ++st) {                                                     \
      _Pragma("unroll")                                                                  \
      for (int mt = 0; mt < 4; ++mt) {                                                   \
        bf16x8 av_ = *(const bf16x8*)(&Vs[VR][(mt * 16 + l16) * 64 + (((st * 4 + quad) ^ h7) << 3)]); \
        o[0][mt] = __builtin_amdgcn_mfma_f32_16x16x32_bf16(av_, pf_[0][st], o[0][mt], 0, 0, 0); \
        o[1][mt] = __builtin_amdgcn_mfma_f32_16x16x32_bf16(av_, pf_[1][st], o[1][mt], 0, 0, 0); \
      }                                                                                  \
    }                                                                                    \
  } while (0)

// pipelined body, iteration t: stage t+1, QK(t)->SN, softmax+PV(t-1) from SP
#define BODY(t, SP, SN, KR, KS)                                                          \
  do {                                                                                   \
    if ((t) < 31) { STAGE_K(KS, (t) + 1); STAGE_V(vn, (t) + 1); }                        \
    int vr_ = vn + 1; if (vr_ == 3) vr_ = 0;                                             \
    QK(SN, KR);                                                                          \
    SOFTMAX_PV(SP, vr_);                                                                 \
    __syncthreads();                                                                     \
    vn = vr_;                                                                            \
  } while (0)

  // ---- prologue: stage tiles 0,1; compute S(0) ----
  STAGE_K(0, 0); STAGE_V(0, 0);
  __syncthreads();                           // tile 0 staged & visible
  STAGE_K(1, 1); STAGE_V(1, 1);              // tile 1 in flight
  QK(sA, 0);                                 // S(0) -> sA (reads Ks[0])
  __syncthreads();                           // tile 1 visible; Ks[0] reads done

  int vn = 2;                                // V stage slot for tile 2 (= (1+1)%3)
  for (int t = 1; t <= 29; t += 2) {
    BODY(t, sA, sB, 1, 0);                   // odd t: S(t)->sB, softmax(t-1) from sA
    BODY(t + 1, sB, sA, 0, 1);               // even:  S(t+1)->sA, softmax(t) from sB
  }
  BODY(31, sA, sB, 1, 0);                    // S(31)->sB, softmax(30) from sA

  // ---- epilogue: softmax + PV for tile 31 (V in slot 31%3 = 1) ----
  {
    int vr_ = vn + 1; if (vr_ == 3) vr_ = 0;
    SOFTMAX_PV(sB, vr_);
  }
#undef BODY
#undef SOFTMAX_PV
#undef QK
#undef STAGE_K
#undef STAGE_V

  int b = bh >> 4, h = bh & 15;
#pragma unroll
  for (int qg = 0; qg < 2; ++qg) {
    float inv_l = 1.f / l_run[qg];
    unsigned short* orow = att + ((size_t)b * 2048 + q0 + qg * 16 + l16) * 1024 + h * 64;
#pragma unroll
    for (int mt = 0; mt < 4; ++mt) {       // O^T: d = mt*16 + quad*4 + reg, q col = l16
      ushort4 ov;
      ov.x = f2bf(o[qg][mt][0] * inv_l);
      ov.y = f2bf(o[qg][mt][1] * inv_l);
      ov.z = f2bf(o[qg][mt][2] * inv_l);
      ov.w = f2bf(o[qg][mt][3] * inv_l);
      *(ushort4*)(orow + mt * 16 + quad * 4) = ov;
    }
  }
}

// ---------- Output projection v2: 128x64 tiles, 512 blocks = 2/CU ----------
// out = att @ Wot^T + bias, fp32 out. Waves 2x2: each 64 rows x 32 cols.
__global__ __launch_bounds__(256) void gemm_out(
    const unsigned short* __restrict__ A, const unsigned short* __restrict__ Bt,
    const float* __restrict__ bias, float* __restrict__ out) {
  __shared__ unsigned short As[128 * 32];  // 8 KB
  __shared__ unsigned short Bs[64 * 32];   // 4 KB
  const int tid = threadIdx.x, wave = tid >> 6, lane = tid & 63;
  const int quad = lane >> 4, l16 = lane & 15;
  const int wm = (wave >> 1) * 64, wn = (wave & 1) * 32;
  const int m0 = blockIdx.y * 128, n0 = blockIdx.x * 64;
  f32x4 acc[4][2];
#pragma unroll
  for (int i = 0; i < 4; ++i)
#pragma unroll
    for (int j = 0; j < 2; ++j) acc[i][j] = zero4();

  const int c = wave * 64 + lane;
  const int rA = c >> 2, o16 = (c & 3) * 8;   // rows 0..63, 8-elem chunk

  for (int k0 = 0; k0 < 1024; k0 += 32) {
    __syncthreads();
    __builtin_amdgcn_global_load_lds(GPTR(A + (size_t)(m0 + rA) * 1024 + k0 + o16),
                                     LPTR(As + wave * 512), 16, 0, 0);
    __builtin_amdgcn_global_load_lds(GPTR(A + (size_t)(m0 + 64 + rA) * 1024 + k0 + o16),
                                     LPTR(As + 2048 + wave * 512), 16, 0, 0);
    __builtin_amdgcn_global_load_lds(GPTR(Bt + (size_t)(n0 + rA) * 1024 + k0 + o16),
                                     LPTR(Bs + wave * 512), 16, 0, 0);
    __syncthreads();
    bf16x8 af[4], bfr[2];
#pragma unroll
    for (int mt = 0; mt < 4; ++mt)
      af[mt] = *(const bf16x8*)(As + (wm + mt * 16 + l16) * 32 + quad * 8);
#pragma unroll
    for (int nt = 0; nt < 2; ++nt)
      bfr[nt] = *(const bf16x8*)(Bs + (wn + nt * 16 + l16) * 32 + quad * 8);
#pragma unroll
    for (int mt = 0; mt < 4; ++mt)
#pragma unroll
      for (int nt = 0; nt < 2; ++nt)
        acc[mt][nt] = __builtin_amdgcn_mfma_f32_16x16x32_bf16(af[mt], bfr[nt], acc[mt][nt], 0, 0, 0);
  }

#pragma unroll
  for (int mt = 0; mt < 4; ++mt) {
#pragma unroll
    for (int nt = 0; nt < 2; ++nt) {
      int m = m0 + wm + mt * 16 + quad * 4;
      int n = n0 + wn + nt * 16 + l16;
      float bv = bias[n];
      float* orow = out + (size_t)m * 1024 + n;
      orow[0]        = acc[mt][nt][0] + bv;
      orow[1024]     = acc[mt][nt][1] + bv;
      orow[2 * 1024] = acc[mt][nt][2] + bv;
      orow[3 * 1024] = acc[mt][nt][3] + bv;
    }
  }
}

extern "C" void kernel_launch(void* const* d_in, const int* in_sizes, int n_in,
                              void* d_out, int out_size, void* d_ws, size_t ws_size,
                              hipStream_t stream) {
  const float* x    = (const float*)d_in[0];   // [2,2048,1024]
  const float* Wqkv = (const float*)d_in[1];   // [1024,3072]
  const float* bqkv = (const float*)d_in[2];   // [3072]
  const float* Wo   = (const float*)d_in[3];   // [1024,1024]
  const float* bo   = (const float*)d_in[4];   // [1024]
  float* out = (float*)d_out;

  // workspace layout (bf16 = unsigned short)
  unsigned short* xb    = (unsigned short*)d_ws;                 // 4096*1024
  unsigned short* wqkvt = xb    + (size_t)4096 * 1024;           // 3072*1024
  unsigned short* wot   = wqkvt + (size_t)3072 * 1024;           // 1024*1024
  unsigned short* Qd    = wot   + (size_t)1024 * 1024;           // [32][2048][64] scaled
  unsigned short* Kd    = Qd    + (size_t)32 * 2048 * 64;        // [32][32][4096] swizzled
  unsigned short* Vtd   = Kd    + (size_t)32 * 2048 * 64;        // [32][32][4096] swizzled
  unsigned short* attb  = Vtd   + (size_t)32 * 2048 * 64;        // 4096*1024

  conv_x_bf16<<<4096, 256, 0, stream>>>(x, xb);
  transpose_conv<<<dim3(48, 16), 256, 0, stream>>>(Wqkv, wqkvt, 1024, 3072);
  transpose_conv<<<dim3(16, 16), 256, 0, stream>>>(Wo, wot, 1024, 1024);
  gemm_qkv<<<dim3(24, 32), 256, 0, stream>>>(xb, wqkvt, bqkv, Qd, Kd, Vtd);
  flash_attn<<<dim3(16, 32), 256, 0, stream>>>(Qd, Kd, Vtd, attb);
  gemm_out<<<dim3(16, 32), 256, 0, stream>>>(attb, wot, bo, out);
}